// Round 11
// baseline (121.121 us; speedup 1.0000x reference)
//
#include <hip/hip_runtime.h>

typedef unsigned short u16;
typedef unsigned int   u32;
typedef __attribute__((ext_vector_type(8))) short bf16x8;
typedef __attribute__((ext_vector_type(4))) float f32x4;

#define LROW 4096
#define NB   8192
#define PCOL 720
#define NPAD 768
#define HH   2048
#define INV_SQRT2F 0.70710678118654752440f

// ws layout: xbf | G | std
#define WS_XBF_BYTES ((size_t)67108864)           // 8192*4096*2
#define WS_G_BYTES   ((size_t)6291456)            // 768*4096*2
#define WS_MIN       (WS_XBF_BYTES + WS_G_BYTES + (size_t)NB * 4)

__device__ __forceinline__ u16 f2bf(float f) {
    union { float f; u32 u; } v; v.f = f;
    u32 r = v.u + 0x7FFFu + ((v.u >> 16) & 1u);
    return (u16)(r >> 16);
}

#define SWZ(i) ((i) ^ (((i) >> 5) & 31))

// ---------------------------------------------------------------------------
// Kernel P: per-row moving-average (via prefix sum), std (ddof=1), x -> bf16
// ---------------------------------------------------------------------------
__global__ __launch_bounds__(256) void prep_rows(const float* __restrict__ x,
                                                 u16* __restrict__ xbf,
                                                 float* __restrict__ stdv) {
    __shared__ float S[LROW];
    __shared__ float wred[4];
    __shared__ float ends[2];
    __shared__ float rred[8];
    const int tid = threadIdx.x;
    const int lane = tid & 63, wv = tid >> 6;
    const size_t b = blockIdx.x;

    const float4* xr4 = (const float4*)(x + b * LROW);
    float4 q0 = xr4[tid * 4 + 0], q1 = xr4[tid * 4 + 1];
    float4 q2 = xr4[tid * 4 + 2], q3 = xr4[tid * 4 + 3];
    float r[16];
    r[0]=q0.x; r[1]=q0.y; r[2]=q0.z; r[3]=q0.w;
    r[4]=q1.x; r[5]=q1.y; r[6]=q1.z; r[7]=q1.w;
    r[8]=q2.x; r[9]=q2.y; r[10]=q2.z; r[11]=q2.w;
    r[12]=q3.x; r[13]=q3.y; r[14]=q3.z; r[15]=q3.w;

    float ps[16];
    float a = 0.f;
    #pragma unroll
    for (int k = 0; k < 16; ++k) { a += r[k]; ps[k] = a; }
    const float segsum = a;

    float v = segsum;
    #pragma unroll
    for (int off = 1; off < 64; off <<= 1) {
        float o = __shfl_up(v, off);
        if (lane >= off) v += o;
    }
    if (lane == 63) wred[wv] = v;
    if (tid == 0)   ends[0] = r[0];
    if (tid == 255) ends[1] = r[15];
    __syncthreads();

    float wbase = 0.f;
    #pragma unroll
    for (int w = 0; w < 4; ++w) if (w < wv) wbase += wred[w];
    const float ebase = wbase + v - segsum;

    #pragma unroll
    for (int k = 0; k < 16; ++k) {
        const int i = (tid << 4) + k;
        S[SWZ(i)] = ebase + ps[k];
    }
    __syncthreads();

    const float x0 = ends[0], xl = ends[1];
    float s1 = 0.f, s2 = 0.f;
    u16 ob[16];
    #pragma unroll
    for (int k = 0; k < 16; ++k) {
        const int i = (tid << 4) + k;
        int h = i + 12; h = h > LROW - 1 ? LROW - 1 : h;
        float wsum = S[SWZ(h)];
        if (i >= 13) wsum -= S[SWZ(i - 13)];
        if (i < 12) wsum += (float)(12 - i) * x0;
        if (i > LROW - 13) wsum += (float)(i - (LROW - 13)) * xl;
        const float xi = r[k];
        const float rr = xi - wsum * 0.04f;
        s1 += rr; s2 += rr * rr;
        ob[k] = f2bf(xi);
    }

    uint4 o0, o1;
    o0.x = (u32)ob[0]  | ((u32)ob[1]  << 16);
    o0.y = (u32)ob[2]  | ((u32)ob[3]  << 16);
    o0.z = (u32)ob[4]  | ((u32)ob[5]  << 16);
    o0.w = (u32)ob[6]  | ((u32)ob[7]  << 16);
    o1.x = (u32)ob[8]  | ((u32)ob[9]  << 16);
    o1.y = (u32)ob[10] | ((u32)ob[11] << 16);
    o1.z = (u32)ob[12] | ((u32)ob[13] << 16);
    o1.w = (u32)ob[14] | ((u32)ob[15] << 16);
    uint4* op = (uint4*)(xbf + b * LROW + ((size_t)tid << 4));
    op[0] = o0; op[1] = o1;

    #pragma unroll
    for (int off = 32; off; off >>= 1) {
        s1 += __shfl_down(s1, off);
        s2 += __shfl_down(s2, off);
    }
    if (lane == 0) { rred[wv * 2] = s1; rred[wv * 2 + 1] = s2; }
    __syncthreads();
    if (tid == 0) {
        const float S1 = rred[0] + rred[2] + rred[4] + rred[6];
        const float S2 = rred[1] + rred[3] + rred[5] + rred[7];
        const float mean = S1 / (float)LROW;
        float var = (S2 - (float)LROW * mean * mean) / (float)(LROW - 1);
        var = var < 0.f ? 0.f : var;
        stdv[b] = sqrtf(var) + 1e-5f;
    }
}

// ---------------------------------------------------------------------------
// Kernel W: fold weights into G[p][l] (bf16), rows 720..767 zero-padded.
// ---------------------------------------------------------------------------
__global__ __launch_bounds__(256) void prep_weights(const float* __restrict__ Wt,
                                                    const float* __restrict__ Wlo,
                                                    const float* __restrict__ Whi,
                                                    u16* __restrict__ Gm) {
    __shared__ float S[LROW];
    __shared__ float wred[4];
    __shared__ float sred[4];
    const int tid = threadIdx.x;
    const int lane = tid & 63, wv = tid >> 6;
    const int p = blockIdx.x;
    u16* grow = Gm + (size_t)p * LROW;
    if (p >= PCOL) {
        uint4 z; z.x = z.y = z.z = z.w = 0u;
        uint4* g4 = (uint4*)grow;
        for (int i = tid; i < LROW / 8; i += 256) g4[i] = z;
        return;
    }
    const float4* wt4 = (const float4*)(Wt + (size_t)p * LROW);
    float4 q0 = wt4[tid * 4 + 0], q1 = wt4[tid * 4 + 1];
    float4 q2 = wt4[tid * 4 + 2], q3 = wt4[tid * 4 + 3];
    const float4* lo4 = (const float4*)(Wlo + (size_t)p * HH);
    const float4* hi4 = (const float4*)(Whi + (size_t)p * HH);
    float4 a0 = lo4[tid * 2 + 0], a1 = lo4[tid * 2 + 1];
    float4 b0 = hi4[tid * 2 + 0], b1 = hi4[tid * 2 + 1];

    float w[16];
    w[0]=q0.x; w[1]=q0.y; w[2]=q0.z; w[3]=q0.w;
    w[4]=q1.x; w[5]=q1.y; w[6]=q1.z; w[7]=q1.w;
    w[8]=q2.x; w[9]=q2.y; w[10]=q2.z; w[11]=q2.w;
    w[12]=q3.x; w[13]=q3.y; w[14]=q3.z; w[15]=q3.w;
    float lv[8] = {a0.x,a0.y,a0.z,a0.w,a1.x,a1.y,a1.z,a1.w};
    float hv[8] = {b0.x,b0.y,b0.z,b0.w,b1.x,b1.y,b1.z,b1.w};

    float u[16], z_[16];
    float slo = 0.f;
    #pragma unroll
    for (int j = 0; j < 8; ++j) {
        u[2*j]   = (lv[j] + hv[j]) * INV_SQRT2F;
        u[2*j+1] = (lv[j] - hv[j]) * INV_SQRT2F;
        slo += lv[j];
    }
    #pragma unroll
    for (int k = 0; k < 16; ++k) z_[k] = w[k] - u[k];

    float ps[16];
    float a = 0.f;
    #pragma unroll
    for (int k = 0; k < 16; ++k) { a += z_[k]; ps[k] = a; }
    const float segsum = a;

    float v = segsum;
    #pragma unroll
    for (int off = 1; off < 64; off <<= 1) {
        float o = __shfl_up(v, off);
        if (lane >= off) v += o;
    }
    if (lane == 63) wred[wv] = v;
    #pragma unroll
    for (int off = 32; off; off >>= 1) slo += __shfl_down(slo, off);
    if (lane == 0) sred[wv] = slo;
    __syncthreads();

    float wbase = 0.f;
    #pragma unroll
    for (int ww = 0; ww < 4; ++ww) if (ww < wv) wbase += wred[ww];
    const float ebase = wbase + v - segsum;
    const float SLO = sred[0] + sred[1] + sred[2] + sred[3];

    #pragma unroll
    for (int k = 0; k < 16; ++k) {
        const int i = (tid << 4) + k;
        S[SWZ(i)] = ebase + ps[k];
    }
    __syncthreads();

    const float coef = -1.4142135623730951f * SLO / (float)LROW;
    u16 ob[16];
    #pragma unroll
    for (int k = 0; k < 16; ++k) {
        const int l = (tid << 4) + k;
        float zT;
        if (l == 0) {
            float acc = 0.f;
            for (int m = 0; m <= 12; ++m) acc += S[SWZ(m)];
            zT = acc * 0.04f;
        } else if (l == LROW - 1) {
            float acc = 0.f;
            for (int m = 0; m <= 12; ++m) acc += S[SWZ(LROW - 2 - m)];
            zT = (13.f * S[SWZ(LROW - 1)] - acc) * 0.04f;
        } else {
            int h = l + 12; h = h > LROW - 1 ? LROW - 1 : h;
            float t_ = S[SWZ(h)];
            if (l >= 13) t_ -= S[SWZ(l - 13)];
            zT = t_ * 0.04f;
        }
        float c;
        const int dmin = l < (LROW - 1 - l) ? l : (LROW - 1 - l);
        if (dmin >= 12)      c = 0.f;
        else if (dmin == 0)  c = -66.f / 25.f;
        else                 c = (float)(12 - dmin) * 0.04f;
        ob[k] = f2bf(zT + u[k] + coef * c);
    }

    uint4 o0, o1;
    o0.x = (u32)ob[0]  | ((u32)ob[1]  << 16);
    o0.y = (u32)ob[2]  | ((u32)ob[3]  << 16);
    o0.z = (u32)ob[4]  | ((u32)ob[5]  << 16);
    o0.w = (u32)ob[6]  | ((u32)ob[7]  << 16);
    o1.x = (u32)ob[8]  | ((u32)ob[9]  << 16);
    o1.y = (u32)ob[10] | ((u32)ob[11] << 16);
    o1.z = (u32)ob[12] | ((u32)ob[13] << 16);
    o1.w = (u32)ob[14] | ((u32)ob[15] << 16);
    uint4* op = (uint4*)(grow + ((size_t)tid << 4));
    op[0] = o0; op[1] = o1;
}

// ---------------------------------------------------------------------------
// Kernel G: fused GEMM, BM=128 BN=96 BK=64, 256 thr = 4 waves (2wm x 2kp),
// wave tile 64x96. R11: A GLOBAL->REG direct (plain C++ loads, L2-hot panel,
// one-iter lead, reg-double-buffered). B in LDS, 3-deep (36KB), stage LEAD-3,
// counted vmcnt(3) retires exactly [B(t+1), A(t)] leaving B(t+2) in flight —
// NO vmcnt(0) in main loop. B frags reg-double-buffered one iter ahead
// (R9 property: MFMA never waits same-iter loads). R9-verbatim B swizzle.
// LDS traffic/CU-iter-pair: 136KB -> 72KB. kp reduce + fused bias epilogue.
// ---------------------------------------------------------------------------
typedef __attribute__((address_space(1))) void gvoid;
typedef __attribute__((address_space(3))) void lvoid;
#define GLD16(g, l_) __builtin_amdgcn_global_load_lds((gvoid*)(g), (lvoid*)(l_), 16, 0, 0)
#define MF(a, b, c) __builtin_amdgcn_mfma_f32_16x16x32_bf16(a, b, c, 0, 0, 0)

#define BBUFB 12288           // 96 rows x 128B per buffer

// stage B tile T into buffer DB (3 gld16/wave; rows wid*24..+24)
#define STAGE_B(T, DB) do { \
    char* db_ = Sm + (DB) * BBUFB + wid * 3072; \
    const size_t go_ = (size_t)(T) * 128; \
    GLD16(sB0 + go_,          db_); \
    GLD16(sB0 + go_ + 65536,  db_ + 1024); \
    GLD16(sB0 + go_ + 131072, db_ + 2048); \
} while (0)

// A tile T -> registers (4 frags, plain loads; compiler manages vmcnt)
#define LOAD_A(T, P) do { \
    const char* s_ = pa + (size_t)(T) * 128; \
    P##0 = *(const bf16x8*)(s_); \
    P##1 = *(const bf16x8*)(s_ + 131072); \
    P##2 = *(const bf16x8*)(s_ + 262144); \
    P##3 = *(const bf16x8*)(s_ + 393216); \
} while (0)

// B frags of tile in buffer DB -> registers (6 ds_read_b128)
#define READ_B(P, DB) do { \
    const char* b_ = Sm + (DB) * BBUFB + bro; \
    P##0 = *(const bf16x8*)(b_); \
    P##1 = *(const bf16x8*)(b_ + 2048); \
    P##2 = *(const bf16x8*)(b_ + 4096); \
    P##3 = *(const bf16x8*)(b_ + 6144); \
    P##4 = *(const bf16x8*)(b_ + 8192); \
    P##5 = *(const bf16x8*)(b_ + 10240); \
} while (0)

#define MFMA24(AP, BP) do { \
    acc[0][0]=MF(AP##0,BP##0,acc[0][0]); acc[0][1]=MF(AP##0,BP##1,acc[0][1]); acc[0][2]=MF(AP##0,BP##2,acc[0][2]); \
    acc[0][3]=MF(AP##0,BP##3,acc[0][3]); acc[0][4]=MF(AP##0,BP##4,acc[0][4]); acc[0][5]=MF(AP##0,BP##5,acc[0][5]); \
    acc[1][0]=MF(AP##1,BP##0,acc[1][0]); acc[1][1]=MF(AP##1,BP##1,acc[1][1]); acc[1][2]=MF(AP##1,BP##2,acc[1][2]); \
    acc[1][3]=MF(AP##1,BP##3,acc[1][3]); acc[1][4]=MF(AP##1,BP##4,acc[1][4]); acc[1][5]=MF(AP##1,BP##5,acc[1][5]); \
    acc[2][0]=MF(AP##2,BP##0,acc[2][0]); acc[2][1]=MF(AP##2,BP##1,acc[2][1]); acc[2][2]=MF(AP##2,BP##2,acc[2][2]); \
    acc[2][3]=MF(AP##2,BP##3,acc[2][3]); acc[2][4]=MF(AP##2,BP##4,acc[2][4]); acc[2][5]=MF(AP##2,BP##5,acc[2][5]); \
    acc[3][0]=MF(AP##3,BP##0,acc[3][0]); acc[3][1]=MF(AP##3,BP##1,acc[3][1]); acc[3][2]=MF(AP##3,BP##2,acc[3][2]); \
    acc[3][3]=MF(AP##3,BP##3,acc[3][3]); acc[3][4]=MF(AP##3,BP##4,acc[3][4]); acc[3][5]=MF(AP##3,BP##5,acc[3][5]); \
} while (0)

// iter t: MFMA on (CA,CB) [loaded last iter]; load A(t+1)->NA (before stage,
// so vmcnt(3) at top of t+1 retires [B(t+2)?, A(t+1)] correctly);
// stage B(t+3)->buf[t%3]; read B-frags(t+1)->NB from buf[(t+1)%3].
#define ITER(T, CA, NA, CB, NB, VM, SBUF, RBUF, DOA, DOSB, DORB) do { \
    asm volatile("s_waitcnt vmcnt(" #VM ") lgkmcnt(0)" ::: "memory"); \
    __builtin_amdgcn_s_barrier(); \
    __builtin_amdgcn_sched_barrier(0); \
    if (DOA)  LOAD_A((T) + 1, NA); \
    if (DOSB) STAGE_B((T) + 3, SBUF); \
    if (DORB) READ_B(NB, RBUF); \
    __builtin_amdgcn_sched_barrier(0); \
    __builtin_amdgcn_s_setprio(1); \
    MFMA24(CA, CB); \
    __builtin_amdgcn_s_setprio(0); \
} while (0)

__global__ __launch_bounds__(256, 2) void gemm_fused(const u16* __restrict__ Abf,
                                                     const u16* __restrict__ Gbf,
                                                     const float* __restrict__ bt,
                                                     const float* __restrict__ bl,
                                                     const float* __restrict__ bh,
                                                     const float* __restrict__ stdv,
                                                     float* __restrict__ out) {
    __shared__ __align__(16) char Sm[53248];   // B 3x12KB; epilogue reduce reuses
    const int tid = threadIdx.x;
    const int l = tid & 63, wid = tid >> 6;    // wid 0..3
    const int wm = wid & 1, kp = wid >> 1;

    // XCD-chunked swizzle: 512 = 8 XCDs x 64; n fastest within chunk
    // (all 8 n-blocks of one m-panel share an XCD -> A panel L2-resident)
    const int orig = blockIdx.x;
    const int chunk = orig & 7, pos = orig >> 3;
    const int bx = pos & 7;
    const int by = (chunk << 3) + (pos >> 3);
    const int m0 = by * 128;
    const int n0 = bx * 96;

    // ---- A: direct global->reg. lane: row (l&15) (+fm*16), 16B at slot l>>4,
    //      k-byte = t*128 + kp*64 ----
    const char* pa = (const char*)Abf
        + ((size_t)(m0 + wm * 64 + (l & 15)) << 13) + kp * 64 + ((l >> 4) << 4);

    // ---- B staging (R9-verbatim XOR pre-swizzle): gld16 covers 8 rows x 128B;
    //      source slot = (l&7)^(l>>3)  ==>  LDS(row, s) = G(row, s ^ (row&7))
    const int sgb = (((l & 7) ^ (l >> 3)) << 4);
    const char* sB0 = (const char*)Gbf + ((size_t)(n0 + wid * 24 + (l >> 3)) << 13) + sgb;

    // ---- B frag read offsets (swizzled k-slot; kp picks slots 0-3/4-7) ----
    const int slot16 = ((((kp << 2) + (l >> 4)) ^ (l & 7)) << 4);
    const int bro = (l & 15) * 128 + slot16;   // fn adds 2048

    f32x4 acc[4][6] = {};
    bf16x8 XA0, XA1, XA2, XA3, YA0, YA1, YA2, YA3;
    bf16x8 XB0, XB1, XB2, XB3, XB4, XB5, YB0, YB1, YB2, YB3, YB4, YB5;

    // ---- prologue: A(0)->XA [4]; B(0,1,2)->buf0,1,2 [9].
    //      vmcnt(6) retires A(0)+B(0), leaves B(1),B(2) in flight. ----
    LOAD_A(0, XA);
    STAGE_B(0, 0);
    STAGE_B(1, 1);
    STAGE_B(2, 2);
    asm volatile("s_waitcnt vmcnt(6)" ::: "memory");
    __builtin_amdgcn_s_barrier();
    __builtin_amdgcn_sched_barrier(0);
    READ_B(XB, 0);

    //      T    CA  NA  CB  NB  VM SB RB  A  S  R
    for (int t = 0; t < 60; t += 6) {
        ITER(t + 0, XA, YA, XB, YB, 3, 0, 1, 1, 1, 1);
        ITER(t + 1, YA, XA, YB, XB, 3, 1, 2, 1, 1, 1);
        ITER(t + 2, XA, YA, XB, YB, 3, 2, 0, 1, 1, 1);
        ITER(t + 3, YA, XA, YB, XB, 3, 0, 1, 1, 1, 1);
        ITER(t + 4, XA, YA, XB, YB, 3, 1, 2, 1, 1, 1);
        ITER(t + 5, YA, XA, YB, XB, 3, 2, 0, 1, 1, 1);
    }
    ITER(60, XA, YA, XB, YB, 3, 0, 1, 1, 1, 1);   // stages B63 -> buf0
    ITER(61, YA, XA, YB, XB, 3, 0, 2, 1, 0, 1);   // no stage; frags62 (buf2)
    ITER(62, XA, YA, XB, YB, 0, 0, 0, 1, 0, 1);   // drain; frags63 (buf0)
    ITER(63, YA, XA, YB, XB, 0, 0, 0, 0, 0, 0);

    // ---- kp-pair reduce (kp1 -> LDS, kp0 adds) + fused bias epilogue ----
    __syncthreads();
    float* red = (float*)Sm;
    const int rr = (l >> 4) << 2;
    const int cc = l & 15;
    const int rbase = wm * 6528;              // 96 cols x 68 floats
    if (kp == 1) {
        #pragma unroll
        for (int m = 0; m < 4; ++m)
            #pragma unroll
            for (int n = 0; n < 6; ++n)
                *(f32x4*)(red + rbase + (n * 16 + cc) * 68 + m * 16 + rr) = acc[m][n];
    }
    __syncthreads();
    if (kp == 0) {
        const int crow = m0 + wm * 64 + rr;
        const int ccol = n0 + cc;
        float btv[6], bsv[6];
        #pragma unroll
        for (int n = 0; n < 6; ++n) {
            const int col = ccol + n * 16;
            if (col < PCOL) { btv[n] = bt[col]; bsv[n] = bl[col] + bh[col]; }
            else            { btv[n] = 0.f; bsv[n] = 0.f; }
        }
        #pragma unroll
        for (int m = 0; m < 4; ++m) {
            const int row = crow + m * 16;
            const float4 sv = *(const float4*)(stdv + row);
            #pragma unroll
            for (int n = 0; n < 6; ++n) {
                const int col = ccol + n * 16;
                if (col < PCOL) {
                    const f32x4 pv = *(const f32x4*)(red + rbase + (n * 16 + cc) * 68 + m * 16 + rr);
                    float* orow = out + (size_t)row * PCOL + col;
                    #pragma unroll
                    for (int j = 0; j < 4; ++j) {
                        const float s = (j == 0) ? sv.x : (j == 1) ? sv.y : (j == 2) ? sv.z : sv.w;
                        orow[(size_t)j * PCOL] = acc[m][n][j] + pv[j] + btv[n] + s * bsv[n];
                    }
                }
            }
        }
    }
}

// ---------------------------------------------------------------------------
extern "C" void kernel_launch(void* const* d_in, const int* in_sizes, int n_in,
                              void* d_out, int out_size, void* d_ws, size_t ws_size,
                              hipStream_t stream) {
    (void)in_sizes; (void)n_in; (void)out_size;
    if (ws_size < WS_MIN) return;

    const float* x  = (const float*)d_in[0];
    const float* Wt = (const float*)d_in[1];
    const float* bt = (const float*)d_in[2];
    const float* Wl = (const float*)d_in[3];
    const float* bl = (const float*)d_in[4];
    const float* Wh = (const float*)d_in[5];
    const float* bh = (const float*)d_in[6];
    float* out = (float*)d_out;

    char* ws = (char*)d_ws;
    u16*   xbf = (u16*)ws;
    u16*   Gm  = (u16*)(ws + WS_XBF_BYTES);
    float* sd  = (float*)(ws + WS_XBF_BYTES + WS_G_BYTES);

    prep_rows<<<NB, 256, 0, stream>>>(x, xbf, sd);
    prep_weights<<<NPAD, 256, 0, stream>>>(Wt, Wl, Wh, Gm);
    gemm_fused<<<512, 256, 0, stream>>>(xbf, Gm, bt, bl, bh, sd, out);
}

// Round 12
// 95.865 us; speedup vs baseline: 1.2634x; 1.2634x over previous
//
#include <hip/hip_runtime.h>

typedef unsigned short u16;
typedef unsigned int   u32;
typedef __attribute__((ext_vector_type(8))) short bf16x8;
typedef __attribute__((ext_vector_type(4))) float f32x4;

#define LROW 4096
#define NB   8192
#define PCOL 720
#define NPAD 768
#define HH   2048
#define INV_SQRT2F 0.70710678118654752440f

// ws layout: xbf | G | std
#define WS_XBF_BYTES ((size_t)67108864)           // 8192*4096*2
#define WS_G_BYTES   ((size_t)6291456)            // 768*4096*2
#define WS_MIN       (WS_XBF_BYTES + WS_G_BYTES + (size_t)NB * 4)

__device__ __forceinline__ u16 f2bf(float f) {
    union { float f; u32 u; } v; v.f = f;
    u32 r = v.u + 0x7FFFu + ((v.u >> 16) & 1u);
    return (u16)(r >> 16);
}

#define SWZ(i) ((i) ^ (((i) >> 5) & 31))

// ---------------------------------------------------------------------------
// Kernel P: per-row moving-average (via prefix sum), std (ddof=1), x -> bf16
// ---------------------------------------------------------------------------
__global__ __launch_bounds__(256) void prep_rows(const float* __restrict__ x,
                                                 u16* __restrict__ xbf,
                                                 float* __restrict__ stdv) {
    __shared__ float S[LROW];
    __shared__ float wred[4];
    __shared__ float ends[2];
    __shared__ float rred[8];
    const int tid = threadIdx.x;
    const int lane = tid & 63, wv = tid >> 6;
    const size_t b = blockIdx.x;

    const float4* xr4 = (const float4*)(x + b * LROW);
    float4 q0 = xr4[tid * 4 + 0], q1 = xr4[tid * 4 + 1];
    float4 q2 = xr4[tid * 4 + 2], q3 = xr4[tid * 4 + 3];
    float r[16];
    r[0]=q0.x; r[1]=q0.y; r[2]=q0.z; r[3]=q0.w;
    r[4]=q1.x; r[5]=q1.y; r[6]=q1.z; r[7]=q1.w;
    r[8]=q2.x; r[9]=q2.y; r[10]=q2.z; r[11]=q2.w;
    r[12]=q3.x; r[13]=q3.y; r[14]=q3.z; r[15]=q3.w;

    float ps[16];
    float a = 0.f;
    #pragma unroll
    for (int k = 0; k < 16; ++k) { a += r[k]; ps[k] = a; }
    const float segsum = a;

    float v = segsum;
    #pragma unroll
    for (int off = 1; off < 64; off <<= 1) {
        float o = __shfl_up(v, off);
        if (lane >= off) v += o;
    }
    if (lane == 63) wred[wv] = v;
    if (tid == 0)   ends[0] = r[0];
    if (tid == 255) ends[1] = r[15];
    __syncthreads();

    float wbase = 0.f;
    #pragma unroll
    for (int w = 0; w < 4; ++w) if (w < wv) wbase += wred[w];
    const float ebase = wbase + v - segsum;

    #pragma unroll
    for (int k = 0; k < 16; ++k) {
        const int i = (tid << 4) + k;
        S[SWZ(i)] = ebase + ps[k];
    }
    __syncthreads();

    const float x0 = ends[0], xl = ends[1];
    float s1 = 0.f, s2 = 0.f;
    u16 ob[16];
    #pragma unroll
    for (int k = 0; k < 16; ++k) {
        const int i = (tid << 4) + k;
        int h = i + 12; h = h > LROW - 1 ? LROW - 1 : h;
        float wsum = S[SWZ(h)];
        if (i >= 13) wsum -= S[SWZ(i - 13)];
        if (i < 12) wsum += (float)(12 - i) * x0;
        if (i > LROW - 13) wsum += (float)(i - (LROW - 13)) * xl;
        const float xi = r[k];
        const float rr = xi - wsum * 0.04f;
        s1 += rr; s2 += rr * rr;
        ob[k] = f2bf(xi);
    }

    uint4 o0, o1;
    o0.x = (u32)ob[0]  | ((u32)ob[1]  << 16);
    o0.y = (u32)ob[2]  | ((u32)ob[3]  << 16);
    o0.z = (u32)ob[4]  | ((u32)ob[5]  << 16);
    o0.w = (u32)ob[6]  | ((u32)ob[7]  << 16);
    o1.x = (u32)ob[8]  | ((u32)ob[9]  << 16);
    o1.y = (u32)ob[10] | ((u32)ob[11] << 16);
    o1.z = (u32)ob[12] | ((u32)ob[13] << 16);
    o1.w = (u32)ob[14] | ((u32)ob[15] << 16);
    uint4* op = (uint4*)(xbf + b * LROW + ((size_t)tid << 4));
    op[0] = o0; op[1] = o1;

    #pragma unroll
    for (int off = 32; off; off >>= 1) {
        s1 += __shfl_down(s1, off);
        s2 += __shfl_down(s2, off);
    }
    if (lane == 0) { rred[wv * 2] = s1; rred[wv * 2 + 1] = s2; }
    __syncthreads();
    if (tid == 0) {
        const float S1 = rred[0] + rred[2] + rred[4] + rred[6];
        const float S2 = rred[1] + rred[3] + rred[5] + rred[7];
        const float mean = S1 / (float)LROW;
        float var = (S2 - (float)LROW * mean * mean) / (float)(LROW - 1);
        var = var < 0.f ? 0.f : var;
        stdv[b] = sqrtf(var) + 1e-5f;
    }
}

// ---------------------------------------------------------------------------
// Kernel W: fold weights into G[p][l] (bf16), rows 720..767 zero-padded.
// ---------------------------------------------------------------------------
__global__ __launch_bounds__(256) void prep_weights(const float* __restrict__ Wt,
                                                    const float* __restrict__ Wlo,
                                                    const float* __restrict__ Whi,
                                                    u16* __restrict__ Gm) {
    __shared__ float S[LROW];
    __shared__ float wred[4];
    __shared__ float sred[4];
    const int tid = threadIdx.x;
    const int lane = tid & 63, wv = tid >> 6;
    const int p = blockIdx.x;
    u16* grow = Gm + (size_t)p * LROW;
    if (p >= PCOL) {
        uint4 z; z.x = z.y = z.z = z.w = 0u;
        uint4* g4 = (uint4*)grow;
        for (int i = tid; i < LROW / 8; i += 256) g4[i] = z;
        return;
    }
    const float4* wt4 = (const float4*)(Wt + (size_t)p * LROW);
    float4 q0 = wt4[tid * 4 + 0], q1 = wt4[tid * 4 + 1];
    float4 q2 = wt4[tid * 4 + 2], q3 = wt4[tid * 4 + 3];
    const float4* lo4 = (const float4*)(Wlo + (size_t)p * HH);
    const float4* hi4 = (const float4*)(Whi + (size_t)p * HH);
    float4 a0 = lo4[tid * 2 + 0], a1 = lo4[tid * 2 + 1];
    float4 b0 = hi4[tid * 2 + 0], b1 = hi4[tid * 2 + 1];

    float w[16];
    w[0]=q0.x; w[1]=q0.y; w[2]=q0.z; w[3]=q0.w;
    w[4]=q1.x; w[5]=q1.y; w[6]=q1.z; w[7]=q1.w;
    w[8]=q2.x; w[9]=q2.y; w[10]=q2.z; w[11]=q2.w;
    w[12]=q3.x; w[13]=q3.y; w[14]=q3.z; w[15]=q3.w;
    float lv[8] = {a0.x,a0.y,a0.z,a0.w,a1.x,a1.y,a1.z,a1.w};
    float hv[8] = {b0.x,b0.y,b0.z,b0.w,b1.x,b1.y,b1.z,b1.w};

    float u[16], z_[16];
    float slo = 0.f;
    #pragma unroll
    for (int j = 0; j < 8; ++j) {
        u[2*j]   = (lv[j] + hv[j]) * INV_SQRT2F;
        u[2*j+1] = (lv[j] - hv[j]) * INV_SQRT2F;
        slo += lv[j];
    }
    #pragma unroll
    for (int k = 0; k < 16; ++k) z_[k] = w[k] - u[k];

    float ps[16];
    float a = 0.f;
    #pragma unroll
    for (int k = 0; k < 16; ++k) { a += z_[k]; ps[k] = a; }
    const float segsum = a;

    float v = segsum;
    #pragma unroll
    for (int off = 1; off < 64; off <<= 1) {
        float o = __shfl_up(v, off);
        if (lane >= off) v += o;
    }
    if (lane == 63) wred[wv] = v;
    #pragma unroll
    for (int off = 32; off; off >>= 1) slo += __shfl_down(slo, off);
    if (lane == 0) sred[wv] = slo;
    __syncthreads();

    float wbase = 0.f;
    #pragma unroll
    for (int ww = 0; ww < 4; ++ww) if (ww < wv) wbase += wred[ww];
    const float ebase = wbase + v - segsum;
    const float SLO = sred[0] + sred[1] + sred[2] + sred[3];

    #pragma unroll
    for (int k = 0; k < 16; ++k) {
        const int i = (tid << 4) + k;
        S[SWZ(i)] = ebase + ps[k];
    }
    __syncthreads();

    const float coef = -1.4142135623730951f * SLO / (float)LROW;
    u16 ob[16];
    #pragma unroll
    for (int k = 0; k < 16; ++k) {
        const int l = (tid << 4) + k;
        float zT;
        if (l == 0) {
            float acc = 0.f;
            for (int m = 0; m <= 12; ++m) acc += S[SWZ(m)];
            zT = acc * 0.04f;
        } else if (l == LROW - 1) {
            float acc = 0.f;
            for (int m = 0; m <= 12; ++m) acc += S[SWZ(LROW - 2 - m)];
            zT = (13.f * S[SWZ(LROW - 1)] - acc) * 0.04f;
        } else {
            int h = l + 12; h = h > LROW - 1 ? LROW - 1 : h;
            float t_ = S[SWZ(h)];
            if (l >= 13) t_ -= S[SWZ(l - 13)];
            zT = t_ * 0.04f;
        }
        float c;
        const int dmin = l < (LROW - 1 - l) ? l : (LROW - 1 - l);
        if (dmin >= 12)      c = 0.f;
        else if (dmin == 0)  c = -66.f / 25.f;
        else                 c = (float)(12 - dmin) * 0.04f;
        ob[k] = f2bf(zT + u[k] + coef * c);
    }

    uint4 o0, o1;
    o0.x = (u32)ob[0]  | ((u32)ob[1]  << 16);
    o0.y = (u32)ob[2]  | ((u32)ob[3]  << 16);
    o0.z = (u32)ob[4]  | ((u32)ob[5]  << 16);
    o0.w = (u32)ob[6]  | ((u32)ob[7]  << 16);
    o1.x = (u32)ob[8]  | ((u32)ob[9]  << 16);
    o1.y = (u32)ob[10] | ((u32)ob[11] << 16);
    o1.z = (u32)ob[12] | ((u32)ob[13] << 16);
    o1.w = (u32)ob[14] | ((u32)ob[15] << 16);
    uint4* op = (uint4*)(grow + ((size_t)tid << 4));
    op[0] = o0; op[1] = o1;
}

// ---------------------------------------------------------------------------
// Kernel G: fused GEMM, BM=128 BN=96 BK=64, 256 thr = 4 waves (2wm x 2kp),
// wave tile 64x96. R12 = R9 + COUNTED VMCNT (T4): A 3-deep (stage lead-3),
// B 2-deep (lead-2); steady-state wait vmcnt(4) retires exactly [S_A(t+1),
// S_B(t+1)] and leaves S_A(t+2) in flight — no vmcnt(0) until the tail.
// Frag sets X/Y reg-double-buffered one iter ahead (R9 property: MFMA never
// waits on same-iter loads). R9-verbatim swizzle/offsets/epilogue. 72KB LDS.
// ---------------------------------------------------------------------------
typedef __attribute__((address_space(1))) void gvoid;
typedef __attribute__((address_space(3))) void lvoid;
#define GLD16(g, l_) __builtin_amdgcn_global_load_lds((gvoid*)(g), (lvoid*)(l_), 16, 0, 0)
#define MF(a, b, c) __builtin_amdgcn_mfma_f32_16x16x32_bf16(a, b, c, 0, 0, 0)

#define ABUFB 16384           // 128 rows x 128B
#define BBASE 49152           // A: 3 x 16KB
#define BBUFB 12288           // 96 rows x 128B

#define STAGE_A(T, DB) do { \
    char* da_ = Sm + (DB) * ABUFB + wid * 4096; \
    const size_t go_ = (size_t)(T) * 128; \
    GLD16(sA0 + go_,          da_); \
    GLD16(sA0 + go_ + 65536,  da_ + 1024); \
    GLD16(sA0 + go_ + 131072, da_ + 2048); \
    GLD16(sA0 + go_ + 196608, da_ + 3072); \
} while (0)

#define STAGE_B(T, DB) do { \
    char* db_ = Sm + BBASE + (DB) * BBUFB + wid * 3072; \
    const size_t go_ = (size_t)(T) * 128; \
    GLD16(sB0 + go_,          db_); \
    GLD16(sB0 + go_ + 65536,  db_ + 1024); \
    GLD16(sB0 + go_ + 131072, db_ + 2048); \
} while (0)

#define READ_FRAGS(P, AB, BB) do { \
    const char* a_ = Sm + (AB) * ABUFB + aro; \
    const char* b_ = Sm + BBASE + (BB) * BBUFB + bro; \
    P##A0 = *(const bf16x8*)(a_); \
    P##A1 = *(const bf16x8*)(a_ + 2048); \
    P##A2 = *(const bf16x8*)(a_ + 4096); \
    P##A3 = *(const bf16x8*)(a_ + 6144); \
    P##B0 = *(const bf16x8*)(b_); \
    P##B1 = *(const bf16x8*)(b_ + 2048); \
    P##B2 = *(const bf16x8*)(b_ + 4096); \
    P##B3 = *(const bf16x8*)(b_ + 6144); \
    P##B4 = *(const bf16x8*)(b_ + 8192); \
    P##B5 = *(const bf16x8*)(b_ + 10240); \
} while (0)

#define MFMA24(P) do { \
    acc[0][0]=MF(P##A0,P##B0,acc[0][0]); acc[0][1]=MF(P##A0,P##B1,acc[0][1]); acc[0][2]=MF(P##A0,P##B2,acc[0][2]); \
    acc[0][3]=MF(P##A0,P##B3,acc[0][3]); acc[0][4]=MF(P##A0,P##B4,acc[0][4]); acc[0][5]=MF(P##A0,P##B5,acc[0][5]); \
    acc[1][0]=MF(P##A1,P##B0,acc[1][0]); acc[1][1]=MF(P##A1,P##B1,acc[1][1]); acc[1][2]=MF(P##A1,P##B2,acc[1][2]); \
    acc[1][3]=MF(P##A1,P##B3,acc[1][3]); acc[1][4]=MF(P##A1,P##B4,acc[1][4]); acc[1][5]=MF(P##A1,P##B5,acc[1][5]); \
    acc[2][0]=MF(P##A2,P##B0,acc[2][0]); acc[2][1]=MF(P##A2,P##B1,acc[2][1]); acc[2][2]=MF(P##A2,P##B2,acc[2][2]); \
    acc[2][3]=MF(P##A2,P##B3,acc[2][3]); acc[2][4]=MF(P##A2,P##B4,acc[2][4]); acc[2][5]=MF(P##A2,P##B5,acc[2][5]); \
    acc[3][0]=MF(P##A3,P##B0,acc[3][0]); acc[3][1]=MF(P##A3,P##B1,acc[3][1]); acc[3][2]=MF(P##A3,P##B2,acc[3][2]); \
    acc[3][3]=MF(P##A3,P##B3,acc[3][3]); acc[3][4]=MF(P##A3,P##B4,acc[3][4]); acc[3][5]=MF(P##A3,P##B5,acc[3][5]); \
} while (0)

// iter t: wait vmcnt(VM)+lgkm(0) [retires frags(t+1)'s stages; leaves
// S_A(t+2) in flight]; barrier; stage S_B(t+2)->Bbuf[t&1], S_A(t+3)->
// Abuf[t%3]; read frags(t+1)->NXT; 24 MFMA on CUR.
#define ITER(T, CUR, NXT, BST, AST, ARD, BRD, VM, SB, SA, RD) do { \
    asm volatile("s_waitcnt vmcnt(" #VM ") lgkmcnt(0)" ::: "memory"); \
    __builtin_amdgcn_s_barrier(); \
    __builtin_amdgcn_sched_barrier(0); \
    if (SB) STAGE_B((T) + 2, BST); \
    if (SA) STAGE_A((T) + 3, AST); \
    __builtin_amdgcn_sched_barrier(0); \
    if (RD) READ_FRAGS(NXT, ARD, BRD); \
    __builtin_amdgcn_sched_barrier(0); \
    __builtin_amdgcn_s_setprio(1); \
    MFMA24(CUR); \
    __builtin_amdgcn_s_setprio(0); \
} while (0)

__global__ __launch_bounds__(256, 2) void gemm_fused(const u16* __restrict__ Abf,
                                                     const u16* __restrict__ Gbf,
                                                     const float* __restrict__ bt,
                                                     const float* __restrict__ bl,
                                                     const float* __restrict__ bh,
                                                     const float* __restrict__ stdv,
                                                     float* __restrict__ out) {
    __shared__ __align__(16) char Sm[73728];   // A 3x16KB | B 2x12KB
    const int tid = threadIdx.x;
    const int l = tid & 63, wid = tid >> 6;    // wid 0..3
    const int wm = wid & 1, kp = wid >> 1;

    // XCD-chunked swizzle: 512 = 8 XCDs x 64; n fastest within chunk
    const int orig = blockIdx.x;
    const int chunk = orig & 7, pos = orig >> 3;
    const int bx = pos & 7;
    const int by = (chunk << 3) + (pos >> 3);
    const int m0 = by * 128;
    const int n0 = bx * 96;

    // ---- staging: each gld16 covers 8 rows x 128B; pre-swizzled source
    //      slot = (l&7)^(l>>3)  ==>  LDS(row, s) = M(row, s ^ (row&7))
    const int sgb = (((l & 7) ^ (l >> 3)) << 4);
    const char* sA0 = (const char*)Abf + ((size_t)(m0 + wid * 32 + (l >> 3)) << 13) + sgb;
    const char* sB0 = (const char*)Gbf + ((size_t)(n0 + wid * 24 + (l >> 3)) << 13) + sgb;

    // ---- fragment read offsets (16x16x32): row base + swizzled k-slot ----
    const int slot16 = ((((kp << 2) + (l >> 4)) ^ (l & 7)) << 4);
    const int aro = (wm * 64 + (l & 15)) * 128 + slot16;   // fm adds 2048
    const int bro = (l & 15) * 128 + slot16;               // fn adds 2048

    f32x4 acc[4][6] = {};
    bf16x8 XA0, XA1, XA2, XA3, XB0, XB1, XB2, XB3, XB4, XB5;
    bf16x8 YA0, YA1, YA2, YA3, YB0, YB1, YB2, YB3, YB4, YB5;

    // ---- prologue: B0,A0 -> buf0; B1,A1 -> buf1; A2 -> abuf2 (18 loads);
    //      vmcnt(11) retires B0+A0; read frags(0) -> X ----
    STAGE_B(0, 0);
    STAGE_A(0, 0);
    STAGE_B(1, 1);
    STAGE_A(1, 1);
    STAGE_A(2, 2);
    asm volatile("s_waitcnt vmcnt(11)" ::: "memory");
    __builtin_amdgcn_s_barrier();
    __builtin_amdgcn_sched_barrier(0);
    READ_FRAGS(X, 0, 0);

    //      T    CUR NXT BST AST ARD BRD VM SB SA RD
    for (int t = 0; t < 60; t += 6) {
        ITER(t + 0, X, Y, 0, 0, 1, 1, 4, 1, 1, 1);
        ITER(t + 1, Y, X, 1, 1, 2, 0, 4, 1, 1, 1);
        ITER(t + 2, X, Y, 0, 2, 0, 1, 4, 1, 1, 1);
        ITER(t + 3, Y, X, 1, 0, 1, 0, 4, 1, 1, 1);
        ITER(t + 4, X, Y, 0, 1, 2, 1, 4, 1, 1, 1);
        ITER(t + 5, Y, X, 1, 2, 0, 0, 4, 1, 1, 1);
    }
    ITER(60, X, Y, 0, 0, 1, 1, 4, 1, 1, 1);   // stages B62->b0, A63->a0
    ITER(61, Y, X, 1, 0, 2, 0, 4, 1, 0, 1);   // stages B63->b1
    ITER(62, X, Y, 0, 0, 0, 1, 0, 0, 0, 1);   // drain; read frags(63)
    ITER(63, Y, X, 0, 0, 0, 0, 0, 0, 0, 0);

    // ---- kp-pair reduce (kp1 -> LDS, kp0 adds) + fused bias epilogue ----
    __syncthreads();
    float* red = (float*)Sm;
    const int rr = (l >> 4) << 2;
    const int cc = l & 15;
    const int rbase = wm * 6528;              // 96 cols x 68 floats
    if (kp == 1) {
        #pragma unroll
        for (int m = 0; m < 4; ++m)
            #pragma unroll
            for (int n = 0; n < 6; ++n)
                *(f32x4*)(red + rbase + (n * 16 + cc) * 68 + m * 16 + rr) = acc[m][n];
    }
    __syncthreads();
    if (kp == 0) {
        const int crow = m0 + wm * 64 + rr;
        const int ccol = n0 + cc;
        float btv[6], bsv[6];
        #pragma unroll
        for (int n = 0; n < 6; ++n) {
            const int col = ccol + n * 16;
            if (col < PCOL) { btv[n] = bt[col]; bsv[n] = bl[col] + bh[col]; }
            else            { btv[n] = 0.f; bsv[n] = 0.f; }
        }
        #pragma unroll
        for (int m = 0; m < 4; ++m) {
            const int row = crow + m * 16;
            const float4 sv = *(const float4*)(stdv + row);
            #pragma unroll
            for (int n = 0; n < 6; ++n) {
                const int col = ccol + n * 16;
                if (col < PCOL) {
                    const f32x4 pv = *(const f32x4*)(red + rbase + (n * 16 + cc) * 68 + m * 16 + rr);
                    float* orow = out + (size_t)row * PCOL + col;
                    #pragma unroll
                    for (int j = 0; j < 4; ++j) {
                        const float s = (j == 0) ? sv.x : (j == 1) ? sv.y : (j == 2) ? sv.z : sv.w;
                        orow[(size_t)j * PCOL] = acc[m][n][j] + pv[j] + btv[n] + s * bsv[n];
                    }
                }
            }
        }
    }
}

// ---------------------------------------------------------------------------
extern "C" void kernel_launch(void* const* d_in, const int* in_sizes, int n_in,
                              void* d_out, int out_size, void* d_ws, size_t ws_size,
                              hipStream_t stream) {
    (void)in_sizes; (void)n_in; (void)out_size;
    if (ws_size < WS_MIN) return;

    const float* x  = (const float*)d_in[0];
    const float* Wt = (const float*)d_in[1];
    const float* bt = (const float*)d_in[2];
    const float* Wl = (const float*)d_in[3];
    const float* bl = (const float*)d_in[4];
    const float* Wh = (const float*)d_in[5];
    const float* bh = (const float*)d_in[6];
    float* out = (float*)d_out;

    char* ws = (char*)d_ws;
    u16*   xbf = (u16*)ws;
    u16*   Gm  = (u16*)(ws + WS_XBF_BYTES);
    float* sd  = (float*)(ws + WS_XBF_BYTES + WS_G_BYTES);

    prep_rows<<<NB, 256, 0, stream>>>(x, xbf, sd);
    prep_weights<<<NPAD, 256, 0, stream>>>(Wt, Wl, Wh, Gm);
    gemm_fused<<<512, 256, 0, stream>>>(xbf, Gm, bt, bl, bh, sd, out);
}